// Round 7
// baseline (98.984 us; speedup 1.0000x reference)
//
#include <hip/hip_runtime.h>
#include <hip/hip_bf16.h>

// GCNConvAdj: out = D^-1/2 (A+I) D^-1/2 (x W) + b
// B=8, N=2048, F_IN=F_OUT=256. f32 in/out; bf16 MFMA internals.
// R7: no adjBF materialization. deg kernel computes dis only (134 MB read).
//     gemm2 stages raw f32 adj via coalesced reg-loads -> +I fold -> bf16
//     -> swizzled ds_write (T14 split); dis[n] applied in epilogue.
#define BB 8
#define NN 2048
#define FF 256
#define NT (NN / 64)   // 32 K-steps of BK=64

typedef __attribute__((ext_vector_type(8))) short short8;
typedef __attribute__((ext_vector_type(4))) short short4v;
typedef __attribute__((ext_vector_type(4))) float f32x4;
typedef __hip_bfloat16 bf16;

__device__ inline short f2bf(float x) {
  unsigned u = __builtin_bit_cast(unsigned, x);
  unsigned r = (u + 0x7fffu + ((u >> 16) & 1u)) >> 16;
  return (short)r;
}

__device__ inline void gl2lds16(const void* g, void* l) {
  __builtin_amdgcn_global_load_lds((const __attribute__((address_space(1))) void*)g,
                                   (__attribute__((address_space(3))) void*)l, 16, 0, 0);
}

// -- kernel 1: deg (dis = rsqrt(rowsum+1)) + wt (WT[o][k] = bf16 W[k][o]) ----
__global__ __launch_bounds__(256)
void deg_wt_kernel(const float* __restrict__ adj, const float* __restrict__ W,
                   float* __restrict__ dis, bf16* __restrict__ WT) {
  if (blockIdx.x >= BB * NN / 4) {
    int t2 = (blockIdx.x - BB * NN / 4) * 256 + threadIdx.x;   // 0..16383
    int k = t2 >> 6, oc = (t2 & 63) * 4;
    float4 v = *reinterpret_cast<const float4*>(W + (size_t)k * FF + oc);
    *reinterpret_cast<short*>(WT + (size_t)(oc + 0) * FF + k) = f2bf(v.x);
    *reinterpret_cast<short*>(WT + (size_t)(oc + 1) * FF + k) = f2bf(v.y);
    *reinterpret_cast<short*>(WT + (size_t)(oc + 2) * FF + k) = f2bf(v.z);
    *reinterpret_cast<short*>(WT + (size_t)(oc + 3) * FF + k) = f2bf(v.w);
    return;
  }
  int wid = threadIdx.x >> 6, lane = threadIdx.x & 63;
  int row = blockIdx.x * 4 + wid;                       // 0 .. BB*NN-1
  const float4* a4 = reinterpret_cast<const float4*>(adj + (size_t)row * NN);
  float4 v[8];
#pragma unroll
  for (int i = 0; i < 4; i++) {                         // all loads in flight
    v[2 * i]     = a4[i * 128 + 2 * lane];
    v[2 * i + 1] = a4[i * 128 + 2 * lane + 1];
  }
  float s = 0.f;
#pragma unroll
  for (int i = 0; i < 8; i++)
    s += v[i].x + v[i].y + v[i].z + v[i].w;
#pragma unroll
  for (int off = 1; off < 64; off <<= 1) s += __shfl_xor(s, off, 64);
  if (lane == 0) dis[row] = rsqrtf(s + 1.0f);
}

// ---------------- kernel 2: gT[b][o][m] = dis[m] * (x@W)[m][o] (bf16) -------
__global__ __launch_bounds__(256)
void gemm1_kernel(const float* __restrict__ x, const bf16* __restrict__ WT,
                  const float* __restrict__ dis, bf16* __restrict__ gT) {
  __shared__ bf16 lA[128][40];
  __shared__ bf16 lB[128][40];
  int bid = blockIdx.x;
  int mtile = bid & 127, otile = bid >> 7;
  int m0 = mtile * 128, o0 = otile * 128;
  int t = threadIdx.x, wid = t >> 6, lane = t & 63;
  int wr = wid >> 1, wc = wid & 1;
  int srow = t >> 1, sseg = t & 1;
  const int r16 = lane & 15, kb = lane >> 4;

  f32x4 acc[4][4];
#pragma unroll
  for (int i = 0; i < 4; i++)
#pragma unroll
    for (int j = 0; j < 4; j++) acc[i][j] = (f32x4){0.f, 0.f, 0.f, 0.f};

  for (int k0 = 0; k0 < FF; k0 += 32) {
    {
      const float4* ap = reinterpret_cast<const float4*>(
          x + (size_t)(m0 + srow) * FF + k0 + sseg * 16);
      float arr[16];
      float4 v0 = ap[0], v1 = ap[1], v2 = ap[2], v3 = ap[3];
      arr[0]=v0.x; arr[1]=v0.y; arr[2]=v0.z; arr[3]=v0.w;
      arr[4]=v1.x; arr[5]=v1.y; arr[6]=v1.z; arr[7]=v1.w;
      arr[8]=v2.x; arr[9]=v2.y; arr[10]=v2.z; arr[11]=v2.w;
      arr[12]=v3.x; arr[13]=v3.y; arr[14]=v3.z; arr[15]=v3.w;
      short8 w0, w1;
#pragma unroll
      for (int e = 0; e < 8; e++) { w0[e] = f2bf(arr[e]); w1[e] = f2bf(arr[8 + e]); }
      *reinterpret_cast<short8*>(&lA[srow][sseg * 16]) = w0;
      *reinterpret_cast<short8*>(&lA[srow][sseg * 16 + 8]) = w1;
    }
    {
      const short8* bp = reinterpret_cast<const short8*>(
          WT + (size_t)(o0 + srow) * FF + k0 + sseg * 16);
      *reinterpret_cast<short8*>(&lB[srow][sseg * 16]) = bp[0];
      *reinterpret_cast<short8*>(&lB[srow][sseg * 16 + 8]) = bp[1];
    }
    __syncthreads();
    short8 af[4], bfr[4];
#pragma unroll
    for (int mf = 0; mf < 4; mf++)
      af[mf] = *reinterpret_cast<const short8*>(&lA[wr * 64 + mf * 16 + r16][kb * 8]);
#pragma unroll
    for (int nf = 0; nf < 4; nf++)
      bfr[nf] = *reinterpret_cast<const short8*>(&lB[wc * 64 + nf * 16 + r16][kb * 8]);
#pragma unroll
    for (int mf = 0; mf < 4; mf++)
#pragma unroll
      for (int nf = 0; nf < 4; nf++)
        acc[mf][nf] = __builtin_amdgcn_mfma_f32_16x16x32_bf16(af[mf], bfr[nf], acc[mf][nf], 0, 0, 0);
    __syncthreads();
  }

  int b = m0 >> 11;
#pragma unroll
  for (int mf = 0; mf < 4; mf++) {
    int mloc = wr * 64 + mf * 16 + (lane >> 4) * 4;
    int mg = m0 + mloc;
    float4 d4 = *reinterpret_cast<const float4*>(dis + mg);
#pragma unroll
    for (int nf = 0; nf < 4; nf++) {
      int o = o0 + wc * 64 + nf * 16 + r16;
      f32x4 v = acc[mf][nf];
      short4v w;
      w[0] = f2bf(v[0] * d4.x); w[1] = f2bf(v[1] * d4.y);
      w[2] = f2bf(v[2] * d4.z); w[3] = f2bf(v[3] * d4.w);
      *reinterpret_cast<short4v*>(gT + ((size_t)b * FF + o) * NN + (mg & (NN - 1))) = w;
    }
  }
}

// ------- kernel 3: out[b][n][o] = dis[n]*((adj+I)@g)[n][o] + bias[o] --------
// BM=BN=BK=64; 1024 blocks = 4/CU. A: raw f32 adj, coalesced reg-load ->
// +I fold -> bf16 -> swizzled ds_write (issue-early/write-late).
// B: gload_lds w/ pre-swizzled source. MFMA path identical to R5.
__global__ __launch_bounds__(256, 4)
void gemm2_kernel(const float* __restrict__ adj, const bf16* __restrict__ gT,
                  const float* __restrict__ dis, const float* __restrict__ bias,
                  float* __restrict__ out) {
  __shared__ __align__(16) bf16 lA[2][64 * 64];    // 8 KB / buf
  __shared__ __align__(16) bf16 lB[2][64 * 64];
  int bid = blockIdx.x;
  // bid%8 invariant across the 4 o-tiles of one (batch,mtile)
  int x3 = bid & 7, idx = bid >> 3;
  int ob = idx & 3, hi = idx >> 2;
  int gg = hi * 8 + x3;                  // [0,256)
  int batch = gg >> 5, mtile = gg & 31;
  int n0 = mtile * 64, o0 = ob * 64;
  const float* Ab = adj + ((size_t)batch * NN + n0) * NN;
  const bf16* Bt = gT + ((size_t)batch * FF + o0) * NN;
  const int dk = n0 >> 6;                // the K-step containing the diagonal

  int t = threadIdx.x, wid = t >> 6, lane = t & 63;
  int wr = wid >> 1, wc = wid & 1;               // 2x2 waves, 32x32 each
  const int r16 = lane & 15, kb = lane >> 4;
  int trow = t >> 3, tslot = t & 7;              // B staging
  int arow = t >> 2, aq = t & 3;                 // A staging: 4 thr/row

  const float4* arp = reinterpret_cast<const float4*>(Ab + (size_t)arow * NN);

  f32x4 acc[2][2];
#pragma unroll
  for (int i = 0; i < 2; i++)
#pragma unroll
    for (int j = 0; j < 2; j++) acc[i][j] = (f32x4){0.f, 0.f, 0.f, 0.f};

  float4 ar0, ar1, ar2, ar3;
  auto loadA = [&](int ks) {
    ar0 = arp[ks * 16 + aq * 4 + 0];
    ar1 = arp[ks * 16 + aq * 4 + 1];
    ar2 = arp[ks * 16 + aq * 4 + 2];
    ar3 = arp[ks * 16 + aq * 4 + 3];
  };
  auto stageB = [&](int buf, int ks) {
#pragma unroll
    for (int q = 0; q < 2; q++) {
      int r = q * 32 + trow;
      int gs = tslot ^ (r & 7);
      gl2lds16(Bt + (size_t)r * NN + ks * 64 + 8 * gs,
               &lB[buf][q * 2048 + wid * 512]);
    }
  };
  auto convA = [&](int buf, int ks) {
    if (ks == dk && (arow >> 4) == aq) {   // diagonal: col == n0+arow
      int e = arow & 15;                    // element index within this thread
      ar0.x += (e == 0);  ar0.y += (e == 1);  ar0.z += (e == 2);  ar0.w += (e == 3);
      ar1.x += (e == 4);  ar1.y += (e == 5);  ar1.z += (e == 6);  ar1.w += (e == 7);
      ar2.x += (e == 8);  ar2.y += (e == 9);  ar2.z += (e == 10); ar2.w += (e == 11);
      ar3.x += (e == 12); ar3.y += (e == 13); ar3.z += (e == 14); ar3.w += (e == 15);
    }
    short8 w0, w1;
    w0[0] = f2bf(ar0.x); w0[1] = f2bf(ar0.y); w0[2] = f2bf(ar0.z); w0[3] = f2bf(ar0.w);
    w0[4] = f2bf(ar1.x); w0[5] = f2bf(ar1.y); w0[6] = f2bf(ar1.z); w0[7] = f2bf(ar1.w);
    w1[0] = f2bf(ar2.x); w1[1] = f2bf(ar2.y); w1[2] = f2bf(ar2.z); w1[3] = f2bf(ar2.w);
    w1[4] = f2bf(ar3.x); w1[5] = f2bf(ar3.y); w1[6] = f2bf(ar3.z); w1[7] = f2bf(ar3.w);
    int s0 = (aq * 2) ^ (arow & 7);
    int s1 = (aq * 2 + 1) ^ (arow & 7);
    *reinterpret_cast<short8*>(&lA[buf][arow * 64 + s0 * 8]) = w0;
    *reinterpret_cast<short8*>(&lA[buf][arow * 64 + s1 * 8]) = w1;
  };

  // prologue
  loadA(0);
  stageB(0, 0);
  convA(0, 0);
  __syncthreads();

  int cur = 0;
#pragma unroll 1
  for (int ks = 0; ks < NT; ++ks) {
    bool more = (ks + 1 < NT);
    int nxt = cur ^ 1;
    if (more) { loadA(ks + 1); stageB(nxt, ks + 1); }
    const bf16* sa = lA[cur];
    const bf16* sb = lB[cur];
    short8 af[2][2], bfr[2][2];
#pragma unroll
    for (int kk = 0; kk < 2; kk++) {
#pragma unroll
      for (int mf = 0; mf < 2; mf++) {
        int ra = wr * 32 + mf * 16 + r16;
        int slot = ((kk << 2) | kb) ^ (ra & 7);
        af[kk][mf] = *reinterpret_cast<const short8*>(&sa[ra * 64 + slot * 8]);
      }
#pragma unroll
      for (int nf = 0; nf < 2; nf++) {
        int rbr = wc * 32 + nf * 16 + r16;
        int slot = ((kk << 2) | kb) ^ (rbr & 7);
        bfr[kk][nf] = *reinterpret_cast<const short8*>(&sb[rbr * 64 + slot * 8]);
      }
    }
    __builtin_amdgcn_s_setprio(1);
#pragma unroll
    for (int kk = 0; kk < 2; kk++)
#pragma unroll
      for (int mf = 0; mf < 2; mf++)
#pragma unroll
        for (int nf = 0; nf < 2; nf++)
          acc[mf][nf] = __builtin_amdgcn_mfma_f32_16x16x32_bf16(
              af[kk][mf], bfr[kk][nf], acc[mf][nf], 0, 0, 0);
    __builtin_amdgcn_s_setprio(0);
    if (more) convA(nxt, ks + 1);     // vmcnt wait on A regs lands here
    __syncthreads();
    cur = nxt;
  }

  // epilogue: out = dis[n]*acc + bias[o]
  const float* disb = dis + (size_t)batch * NN;
  float bv[2];
#pragma unroll
  for (int nf = 0; nf < 2; nf++) bv[nf] = bias[o0 + wc * 32 + nf * 16 + r16];
#pragma unroll
  for (int mf = 0; mf < 2; mf++) {
    int ng = n0 + wr * 32 + mf * 16 + (lane >> 4) * 4;
    float4 d4 = *reinterpret_cast<const float4*>(disb + ng);
    float* op0 = out + ((size_t)batch * NN + ng) * FF;
#pragma unroll
    for (int nf = 0; nf < 2; nf++) {
      int o = o0 + wc * 32 + nf * 16 + r16;
      f32x4 v = acc[mf][nf];
      op0[0 * FF + o] = v[0] * d4.x + bv[nf];
      op0[1 * FF + o] = v[1] * d4.y + bv[nf];
      op0[2 * FF + o] = v[2] * d4.z + bv[nf];
      op0[3 * FF + o] = v[3] * d4.w + bv[nf];
    }
  }
}

extern "C" void kernel_launch(void* const* d_in, const int* in_sizes, int n_in,
                              void* d_out, int out_size, void* d_ws, size_t ws_size,
                              hipStream_t stream) {
  const float* x    = (const float*)d_in[0];
  const float* adj  = (const float*)d_in[1];
  const float* W    = (const float*)d_in[2];
  const float* bias = (const float*)d_in[3];
  float* out = (float*)d_out;

  char* ws = (char*)d_ws;
  float* dis = (float*)ws;                   // 64 KB
  bf16* WT   = (bf16*)(ws + (64 << 10));     // 128 KB
  bf16* gT   = (bf16*)(ws + (192 << 10));    // 8 MB

  deg_wt_kernel<<<BB * NN / 4 + 64, 256, 0, stream>>>(adj, W, dis, WT);
  gemm1_kernel<<<256, 256, 0, stream>>>(x, WT, dis, gT);
  gemm2_kernel<<<1024, 256, 0, stream>>>(adj, gT, dis, bias, out);
}

// Round 8
// 88.507 us; speedup vs baseline: 1.1184x; 1.1184x over previous
//
#include <hip/hip_runtime.h>
#include <hip/hip_bf16.h>

// GCNConvAdj: out = D^-1/2 (A+I) D^-1/2 (x W) + b
// B=8, N=2048, F_IN=F_OUT=256. f32 in/out; bf16 MFMA internals.
// R8: K1 deg+wt (pure 134MB read). K2 = convert(adjBF, L3-fed) || gemm1
//     (merged launch, disjoint block ranges). K3 = gemm2 (R5 exact).
#define BB 8
#define NN 2048
#define FF 256
#define NT (NN / 64)   // 32 K-steps of BK=64

typedef __attribute__((ext_vector_type(8))) short short8;
typedef __attribute__((ext_vector_type(4))) short short4v;
typedef __attribute__((ext_vector_type(4))) float f32x4;
typedef __hip_bfloat16 bf16;

__device__ inline short f2bf(float x) {
  unsigned u = __builtin_bit_cast(unsigned, x);
  unsigned r = (u + 0x7fffu + ((u >> 16) & 1u)) >> 16;
  return (short)r;
}

__device__ inline void gl2lds16(const void* g, void* l) {
  __builtin_amdgcn_global_load_lds((const __attribute__((address_space(1))) void*)g,
                                   (__attribute__((address_space(3))) void*)l, 16, 0, 0);
}

// -- kernel 1: deg (dis = rsqrt(rowsum+1)) + wt (WT[o][k] = bf16 W[k][o]) ----
__global__ __launch_bounds__(256)
void deg_wt_kernel(const float* __restrict__ adj, const float* __restrict__ W,
                   float* __restrict__ dis, bf16* __restrict__ WT) {
  if (blockIdx.x >= BB * NN / 4) {
    int t2 = (blockIdx.x - BB * NN / 4) * 256 + threadIdx.x;   // 0..16383
    int k = t2 >> 6, oc = (t2 & 63) * 4;
    float4 v = *reinterpret_cast<const float4*>(W + (size_t)k * FF + oc);
    *reinterpret_cast<short*>(WT + (size_t)(oc + 0) * FF + k) = f2bf(v.x);
    *reinterpret_cast<short*>(WT + (size_t)(oc + 1) * FF + k) = f2bf(v.y);
    *reinterpret_cast<short*>(WT + (size_t)(oc + 2) * FF + k) = f2bf(v.z);
    *reinterpret_cast<short*>(WT + (size_t)(oc + 3) * FF + k) = f2bf(v.w);
    return;
  }
  int wid = threadIdx.x >> 6, lane = threadIdx.x & 63;
  int row = blockIdx.x * 4 + wid;                       // 0 .. BB*NN-1
  const float4* a4 = reinterpret_cast<const float4*>(adj + (size_t)row * NN);
  float4 v[8];
#pragma unroll
  for (int i = 0; i < 4; i++) {                         // all loads in flight
    v[2 * i]     = a4[i * 128 + 2 * lane];
    v[2 * i + 1] = a4[i * 128 + 2 * lane + 1];
  }
  float s = 0.f;
#pragma unroll
  for (int i = 0; i < 8; i++)
    s += v[i].x + v[i].y + v[i].z + v[i].w;
#pragma unroll
  for (int off = 1; off < 64; off <<= 1) s += __shfl_xor(s, off, 64);
  if (lane == 0) dis[row] = rsqrtf(s + 1.0f);
}

// -- kernel 2: blocks [0,256): gemm1  |  blocks [256,4352): convert ----------
// gemm1: gT[b][o][m] = dis[m]*(x@W)[m][o]  (bf16, o-major)
// convert: adjBF[r][m] = bf16(dis[r]*(adj[r][m] + I))   (adj is L3-warm)
__global__ __launch_bounds__(256)
void conv_gemm1_kernel(const float* __restrict__ adj, const float* __restrict__ x,
                       const bf16* __restrict__ WT, const float* __restrict__ dis,
                       bf16* __restrict__ gT, bf16* __restrict__ adjBF) {
  if (blockIdx.x >= 256) {
    // ---- convert: 4096 blocks, 4 rows each (1 wave/row) ----
    int wid = threadIdx.x >> 6, lane = threadIdx.x & 63;
    int row = (blockIdx.x - 256) * 4 + wid;             // 0 .. BB*NN-1
    const float4* a4 = reinterpret_cast<const float4*>(adj + (size_t)row * NN);
    float4 v[8];
#pragma unroll
    for (int i = 0; i < 4; i++) {
      v[2 * i]     = a4[i * 128 + 2 * lane];
      v[2 * i + 1] = a4[i * 128 + 2 * lane + 1];
    }
    float d = dis[row];
    int rb = row & (NN - 1);
#pragma unroll
    for (int i = 0; i < 8; i++) {
      int dd = rb - ((i >> 1) * 512 + 8 * lane + 4 * (i & 1));
      v[i].x += (dd == 0) ? 1.0f : 0.0f;
      v[i].y += (dd == 1) ? 1.0f : 0.0f;
      v[i].z += (dd == 2) ? 1.0f : 0.0f;
      v[i].w += (dd == 3) ? 1.0f : 0.0f;
    }
    bf16* orow = adjBF + (size_t)row * NN;
#pragma unroll
    for (int i = 0; i < 4; i++) {
      short8 w;
      w[0] = f2bf(v[2*i].x * d);   w[1] = f2bf(v[2*i].y * d);
      w[2] = f2bf(v[2*i].z * d);   w[3] = f2bf(v[2*i].w * d);
      w[4] = f2bf(v[2*i+1].x * d); w[5] = f2bf(v[2*i+1].y * d);
      w[6] = f2bf(v[2*i+1].z * d); w[7] = f2bf(v[2*i+1].w * d);
      *reinterpret_cast<short8*>(orow + i * 512 + 8 * lane) = w;
    }
    return;
  }
  // ---- gemm1: 256 blocks ----
  __shared__ bf16 lA[128][40];
  __shared__ bf16 lB[128][40];
  int bid = blockIdx.x;
  int mtile = bid & 127, otile = bid >> 7;
  int m0 = mtile * 128, o0 = otile * 128;
  int t = threadIdx.x, wid = t >> 6, lane = t & 63;
  int wr = wid >> 1, wc = wid & 1;
  int srow = t >> 1, sseg = t & 1;
  const int r16 = lane & 15, kb = lane >> 4;

  f32x4 acc[4][4];
#pragma unroll
  for (int i = 0; i < 4; i++)
#pragma unroll
    for (int j = 0; j < 4; j++) acc[i][j] = (f32x4){0.f, 0.f, 0.f, 0.f};

  for (int k0 = 0; k0 < FF; k0 += 32) {
    {
      const float4* ap = reinterpret_cast<const float4*>(
          x + (size_t)(m0 + srow) * FF + k0 + sseg * 16);
      float arr[16];
      float4 v0 = ap[0], v1 = ap[1], v2 = ap[2], v3 = ap[3];
      arr[0]=v0.x; arr[1]=v0.y; arr[2]=v0.z; arr[3]=v0.w;
      arr[4]=v1.x; arr[5]=v1.y; arr[6]=v1.z; arr[7]=v1.w;
      arr[8]=v2.x; arr[9]=v2.y; arr[10]=v2.z; arr[11]=v2.w;
      arr[12]=v3.x; arr[13]=v3.y; arr[14]=v3.z; arr[15]=v3.w;
      short8 w0, w1;
#pragma unroll
      for (int e = 0; e < 8; e++) { w0[e] = f2bf(arr[e]); w1[e] = f2bf(arr[8 + e]); }
      *reinterpret_cast<short8*>(&lA[srow][sseg * 16]) = w0;
      *reinterpret_cast<short8*>(&lA[srow][sseg * 16 + 8]) = w1;
    }
    {
      const short8* bp = reinterpret_cast<const short8*>(
          WT + (size_t)(o0 + srow) * FF + k0 + sseg * 16);
      *reinterpret_cast<short8*>(&lB[srow][sseg * 16]) = bp[0];
      *reinterpret_cast<short8*>(&lB[srow][sseg * 16 + 8]) = bp[1];
    }
    __syncthreads();
    short8 af[4], bfr[4];
#pragma unroll
    for (int mf = 0; mf < 4; mf++)
      af[mf] = *reinterpret_cast<const short8*>(&lA[wr * 64 + mf * 16 + r16][kb * 8]);
#pragma unroll
    for (int nf = 0; nf < 4; nf++)
      bfr[nf] = *reinterpret_cast<const short8*>(&lB[wc * 64 + nf * 16 + r16][kb * 8]);
#pragma unroll
    for (int mf = 0; mf < 4; mf++)
#pragma unroll
      for (int nf = 0; nf < 4; nf++)
        acc[mf][nf] = __builtin_amdgcn_mfma_f32_16x16x32_bf16(af[mf], bfr[nf], acc[mf][nf], 0, 0, 0);
    __syncthreads();
  }

  int b = m0 >> 11;
#pragma unroll
  for (int mf = 0; mf < 4; mf++) {
    int mloc = wr * 64 + mf * 16 + (lane >> 4) * 4;
    int mg = m0 + mloc;
    float4 d4 = *reinterpret_cast<const float4*>(dis + mg);
#pragma unroll
    for (int nf = 0; nf < 4; nf++) {
      int o = o0 + wc * 64 + nf * 16 + r16;
      f32x4 v = acc[mf][nf];
      short4v w;
      w[0] = f2bf(v[0] * d4.x); w[1] = f2bf(v[1] * d4.y);
      w[2] = f2bf(v[2] * d4.z); w[3] = f2bf(v[3] * d4.w);
      *reinterpret_cast<short4v*>(gT + ((size_t)b * FF + o) * NN + (mg & (NN - 1))) = w;
    }
  }
}

// ------- kernel 3: out[b][n][o] = (adjBF @ gT^T)[n][o] + bias[o] ------------
// R5 exact: BM=BN=BK=64; 1024 blocks = 4/CU. All-gload_lds, both-sides
// slot swizzle, stage-before-compute, setprio on MFMA cluster.
__global__ __launch_bounds__(256, 4)
void gemm2_kernel(const bf16* __restrict__ adjBF, const bf16* __restrict__ gT,
                  const float* __restrict__ bias, float* __restrict__ out) {
  __shared__ __align__(16) bf16 lA[2][64 * 64];    // 8 KB each buf
  __shared__ __align__(16) bf16 lB[2][64 * 64];
  int bid = blockIdx.x;
  int x3 = bid & 7, idx = bid >> 3;
  int ob = idx & 3, hi = idx >> 2;
  int gg = hi * 8 + x3;                  // [0,256)
  int batch = gg >> 5, mtile = gg & 31;
  int n0 = mtile * 64, o0 = ob * 64;
  const bf16* Ab = adjBF + ((size_t)batch * NN + n0) * NN;
  const bf16* Bt = gT + ((size_t)batch * FF + o0) * NN;

  int t = threadIdx.x, wid = t >> 6, lane = t & 63;
  int wr = wid >> 1, wc = wid & 1;               // 2x2 waves, 32x32 each
  const int r16 = lane & 15, kb = lane >> 4;
  int trow = t >> 3, tslot = t & 7;

  f32x4 acc[2][2];
#pragma unroll
  for (int i = 0; i < 2; i++)
#pragma unroll
    for (int j = 0; j < 2; j++) acc[i][j] = (f32x4){0.f, 0.f, 0.f, 0.f};

  auto stage = [&](int buf, int ks) {
    bf16* la = &lA[buf][wid * 512];
    bf16* lb = &lB[buf][wid * 512];
#pragma unroll
    for (int q = 0; q < 2; q++) {
      int r = q * 32 + trow;
      int gs = tslot ^ (r & 7);
      gl2lds16(Ab + (size_t)r * NN + ks * 64 + 8 * gs, la + q * 2048);
      gl2lds16(Bt + (size_t)r * NN + ks * 64 + 8 * gs, lb + q * 2048);
    }
  };

  stage(0, 0);
  __syncthreads();
  int cur = 0;
#pragma unroll 1
  for (int ks = 0; ks < NT; ++ks) {
    if (ks + 1 < NT) stage(cur ^ 1, ks + 1);
    const bf16* sa = lA[cur];
    const bf16* sb = lB[cur];
    short8 af[2][2], bfr[2][2];
#pragma unroll
    for (int kk = 0; kk < 2; kk++) {
#pragma unroll
      for (int mf = 0; mf < 2; mf++) {
        int ra = wr * 32 + mf * 16 + r16;
        int slot = ((kk << 2) | kb) ^ (ra & 7);
        af[kk][mf] = *reinterpret_cast<const short8*>(&sa[ra * 64 + slot * 8]);
      }
#pragma unroll
      for (int nf = 0; nf < 2; nf++) {
        int rbr = wc * 32 + nf * 16 + r16;
        int slot = ((kk << 2) | kb) ^ (rbr & 7);
        bfr[kk][nf] = *reinterpret_cast<const short8*>(&sb[rbr * 64 + slot * 8]);
      }
    }
    __builtin_amdgcn_s_setprio(1);
#pragma unroll
    for (int kk = 0; kk < 2; kk++)
#pragma unroll
      for (int mf = 0; mf < 2; mf++)
#pragma unroll
        for (int nf = 0; nf < 2; nf++)
          acc[mf][nf] = __builtin_amdgcn_mfma_f32_16x16x32_bf16(
              af[kk][mf], bfr[kk][nf], acc[mf][nf], 0, 0, 0);
    __builtin_amdgcn_s_setprio(0);
    __syncthreads();
    cur ^= 1;
  }

  float bv[2];
#pragma unroll
  for (int nf = 0; nf < 2; nf++) bv[nf] = bias[o0 + wc * 32 + nf * 16 + r16];
#pragma unroll
  for (int mf = 0; mf < 2; mf++) {
    int ng = n0 + wr * 32 + mf * 16 + (lane >> 4) * 4;
    float* op0 = out + ((size_t)batch * NN + ng) * FF;
#pragma unroll
    for (int nf = 0; nf < 2; nf++) {
      int o = o0 + wc * 32 + nf * 16 + r16;
      f32x4 v = acc[mf][nf];
      op0[0 * FF + o] = v[0] + bv[nf];
      op0[1 * FF + o] = v[1] + bv[nf];
      op0[2 * FF + o] = v[2] + bv[nf];
      op0[3 * FF + o] = v[3] + bv[nf];
    }
  }
}

extern "C" void kernel_launch(void* const* d_in, const int* in_sizes, int n_in,
                              void* d_out, int out_size, void* d_ws, size_t ws_size,
                              hipStream_t stream) {
  const float* x    = (const float*)d_in[0];
  const float* adj  = (const float*)d_in[1];
  const float* W    = (const float*)d_in[2];
  const float* bias = (const float*)d_in[3];
  float* out = (float*)d_out;

  char* ws = (char*)d_ws;
  float* dis  = (float*)ws;                              // 64 KB
  bf16* WT    = (bf16*)(ws + (64 << 10));                // 128 KB
  bf16* gT    = (bf16*)(ws + (192 << 10));               // 8 MB
  bf16* adjBF = (bf16*)(ws + (192 << 10) + (8 << 20));   // 64 MB

  deg_wt_kernel<<<BB * NN / 4 + 64, 256, 0, stream>>>(adj, W, dis, WT);
  conv_gemm1_kernel<<<256 + BB * NN / 4, 256, 0, stream>>>(adj, x, WT, dis, gT, adjBF);
  gemm2_kernel<<<1024, 256, 0, stream>>>(adjBF, gT, bias, out);
}

// Round 10
// 80.325 us; speedup vs baseline: 1.2323x; 1.1018x over previous
//
#include <hip/hip_runtime.h>
#include <hip/hip_bf16.h>

// GCNConvAdj: out = D^-1/2 (A+I) D^-1/2 (x W) + b
// B=8, N=2048, F_IN=F_OUT=256. f32 in/out; bf16 MFMA internals.
// R10 (=R9 fixed): R5 structure + (a) nontemporal adj loads in degconv
//     (don't pollute L3; adjBF/gT stay resident for gemm2), (b) packed
//     v_cvt_pk_bf16_f32 conversions, (c) gemm2 = R5 exact.
#define BB 8
#define NN 2048
#define FF 256
#define NT (NN / 64)   // 32 K-steps of BK=64

typedef __attribute__((ext_vector_type(8))) short short8;
typedef __attribute__((ext_vector_type(4))) float f32x4;
typedef __hip_bfloat16 bf16;

__device__ inline unsigned pk2(float a, float b) {
  __hip_bfloat162 h = __float22bfloat162_rn(make_float2(a, b));  // v_cvt_pk_bf16_f32
  unsigned r;
  __builtin_memcpy(&r, &h, 4);
  return r;
}

__device__ inline short f2bf(float x) {
  unsigned u = __builtin_bit_cast(unsigned, x);
  unsigned r = (u + 0x7fffu + ((u >> 16) & 1u)) >> 16;
  return (short)r;
}

__device__ inline void gl2lds16(const void* g, void* l) {
  __builtin_amdgcn_global_load_lds((const __attribute__((address_space(1))) void*)g,
                                   (__attribute__((address_space(3))) void*)l, 16, 0, 0);
}

// -- kernel 1: deg + convert (adjBF = bf16(dis_r*(adj+I))) + wt (WT bf16) ----
__global__ __launch_bounds__(256)
void degconv_wt_kernel(const float* __restrict__ adj, const float* __restrict__ W,
                       float* __restrict__ dis, bf16* __restrict__ WT,
                       bf16* __restrict__ adjBF) {
  if (blockIdx.x >= BB * NN / 4) {
    int t2 = (blockIdx.x - BB * NN / 4) * 256 + threadIdx.x;   // 0..16383
    int k = t2 >> 6, oc = (t2 & 63) * 4;
    float4 v = *reinterpret_cast<const float4*>(W + (size_t)k * FF + oc);
    *reinterpret_cast<short*>(WT + (size_t)(oc + 0) * FF + k) = f2bf(v.x);
    *reinterpret_cast<short*>(WT + (size_t)(oc + 1) * FF + k) = f2bf(v.y);
    *reinterpret_cast<short*>(WT + (size_t)(oc + 2) * FF + k) = f2bf(v.z);
    *reinterpret_cast<short*>(WT + (size_t)(oc + 3) * FF + k) = f2bf(v.w);
    return;
  }
  int wid = threadIdx.x >> 6, lane = threadIdx.x & 63;
  int row = blockIdx.x * 4 + wid;                       // 0 .. BB*NN-1
  const f32x4* a4 = reinterpret_cast<const f32x4*>(adj + (size_t)row * NN);
  f32x4 v[8];
#pragma unroll
  for (int i = 0; i < 4; i++) {                  // NT loads: adj dead after this
    v[2 * i]     = __builtin_nontemporal_load(a4 + i * 128 + 2 * lane);
    v[2 * i + 1] = __builtin_nontemporal_load(a4 + i * 128 + 2 * lane + 1);
  }
  float s = 0.f;
#pragma unroll
  for (int i = 0; i < 8; i++)
    s += v[i][0] + v[i][1] + v[i][2] + v[i][3];
#pragma unroll
  for (int off = 1; off < 64; off <<= 1) s += __shfl_xor(s, off, 64);
  float d = rsqrtf(s + 1.0f);
  if (lane == 0) dis[row] = d;
  int rb = row & (NN - 1);
#pragma unroll
  for (int i = 0; i < 8; i++) {
    int dd = rb - ((i >> 1) * 512 + 8 * lane + 4 * (i & 1));
    v[i][0] += (dd == 0) ? 1.0f : 0.0f;
    v[i][1] += (dd == 1) ? 1.0f : 0.0f;
    v[i][2] += (dd == 2) ? 1.0f : 0.0f;
    v[i][3] += (dd == 3) ? 1.0f : 0.0f;
  }
  bf16* orow = adjBF + (size_t)row * NN;
#pragma unroll
  for (int i = 0; i < 4; i++) {
    uint4 w;
    w.x = pk2(v[2*i][0] * d,   v[2*i][1] * d);
    w.y = pk2(v[2*i][2] * d,   v[2*i][3] * d);
    w.z = pk2(v[2*i+1][0] * d, v[2*i+1][1] * d);
    w.w = pk2(v[2*i+1][2] * d, v[2*i+1][3] * d);
    *reinterpret_cast<uint4*>(orow + i * 512 + 8 * lane) = w;
  }
}

// ---------------- kernel 2: gT[b][o][m] = dis[m] * (x@W)[m][o] (bf16) -------
__global__ __launch_bounds__(256)
void gemm1_kernel(const float* __restrict__ x, const bf16* __restrict__ WT,
                  const float* __restrict__ dis, bf16* __restrict__ gT) {
  __shared__ bf16 lA[128][40];
  __shared__ bf16 lB[128][40];
  int bid = blockIdx.x;
  int mtile = bid & 127, otile = bid >> 7;
  int m0 = mtile * 128, o0 = otile * 128;
  int t = threadIdx.x, wid = t >> 6, lane = t & 63;
  int wr = wid >> 1, wc = wid & 1;
  int srow = t >> 1, sseg = t & 1;
  const int r16 = lane & 15, kb = lane >> 4;

  f32x4 acc[4][4];
#pragma unroll
  for (int i = 0; i < 4; i++)
#pragma unroll
    for (int j = 0; j < 4; j++) acc[i][j] = (f32x4){0.f, 0.f, 0.f, 0.f};

  for (int k0 = 0; k0 < FF; k0 += 32) {
    {
      const float4* ap = reinterpret_cast<const float4*>(
          x + (size_t)(m0 + srow) * FF + k0 + sseg * 16);
      float4 v0 = ap[0], v1 = ap[1], v2 = ap[2], v3 = ap[3];
      uint4 w0, w1;
      w0.x = pk2(v0.x, v0.y); w0.y = pk2(v0.z, v0.w);
      w0.z = pk2(v1.x, v1.y); w0.w = pk2(v1.z, v1.w);
      w1.x = pk2(v2.x, v2.y); w1.y = pk2(v2.z, v2.w);
      w1.z = pk2(v3.x, v3.y); w1.w = pk2(v3.z, v3.w);
      *reinterpret_cast<uint4*>(&lA[srow][sseg * 16]) = w0;
      *reinterpret_cast<uint4*>(&lA[srow][sseg * 16 + 8]) = w1;
    }
    {
      const short8* bp = reinterpret_cast<const short8*>(
          WT + (size_t)(o0 + srow) * FF + k0 + sseg * 16);
      *reinterpret_cast<short8*>(&lB[srow][sseg * 16]) = bp[0];
      *reinterpret_cast<short8*>(&lB[srow][sseg * 16 + 8]) = bp[1];
    }
    __syncthreads();
    short8 af[4], bfr[4];
#pragma unroll
    for (int mf = 0; mf < 4; mf++)
      af[mf] = *reinterpret_cast<const short8*>(&lA[wr * 64 + mf * 16 + r16][kb * 8]);
#pragma unroll
    for (int nf = 0; nf < 4; nf++)
      bfr[nf] = *reinterpret_cast<const short8*>(&lB[wc * 64 + nf * 16 + r16][kb * 8]);
#pragma unroll
    for (int mf = 0; mf < 4; mf++)
#pragma unroll
      for (int nf = 0; nf < 4; nf++)
        acc[mf][nf] = __builtin_amdgcn_mfma_f32_16x16x32_bf16(af[mf], bfr[nf], acc[mf][nf], 0, 0, 0);
    __syncthreads();
  }

  int b = m0 >> 11;
#pragma unroll
  for (int mf = 0; mf < 4; mf++) {
    int mloc = wr * 64 + mf * 16 + (lane >> 4) * 4;
    int mg = m0 + mloc;
    float4 d4 = *reinterpret_cast<const float4*>(dis + mg);
#pragma unroll
    for (int nf = 0; nf < 4; nf++) {
      int o = o0 + wc * 64 + nf * 16 + r16;
      f32x4 v = acc[mf][nf];
      uint2 w;
      w.x = pk2(v[0] * d4.x, v[1] * d4.y);
      w.y = pk2(v[2] * d4.z, v[3] * d4.w);
      *reinterpret_cast<uint2*>(gT + ((size_t)b * FF + o) * NN + (mg & (NN - 1))) = w;
    }
  }
}

// ------- kernel 3: out[b][n][o] = (adjBF @ gT^T)[n][o] + bias[o] ------------
// R5 exact: BM=BN=BK=64; 1024 blocks = 4/CU. All-gload_lds, both-sides
// slot swizzle, stage-before-compute, setprio on MFMA cluster.
__global__ __launch_bounds__(256, 4)
void gemm2_kernel(const bf16* __restrict__ adjBF, const bf16* __restrict__ gT,
                  const float* __restrict__ bias, float* __restrict__ out) {
  __shared__ __align__(16) bf16 lA[2][64 * 64];    // 8 KB each buf
  __shared__ __align__(16) bf16 lB[2][64 * 64];
  int bid = blockIdx.x;
  int x3 = bid & 7, idx = bid >> 3;
  int ob = idx & 3, hi = idx >> 2;
  int gg = hi * 8 + x3;                  // [0,256)
  int batch = gg >> 5, mtile = gg & 31;
  int n0 = mtile * 64, o0 = ob * 64;
  const bf16* Ab = adjBF + ((size_t)batch * NN + n0) * NN;
  const bf16* Bt = gT + ((size_t)batch * FF + o0) * NN;

  int t = threadIdx.x, wid = t >> 6, lane = t & 63;
  int wr = wid >> 1, wc = wid & 1;               // 2x2 waves, 32x32 each
  const int r16 = lane & 15, kb = lane >> 4;
  int trow = t >> 3, tslot = t & 7;

  f32x4 acc[2][2];
#pragma unroll
  for (int i = 0; i < 2; i++)
#pragma unroll
    for (int j = 0; j < 2; j++) acc[i][j] = (f32x4){0.f, 0.f, 0.f, 0.f};

  auto stage = [&](int buf, int ks) {
    bf16* la = &lA[buf][wid * 512];
    bf16* lb = &lB[buf][wid * 512];
#pragma unroll
    for (int q = 0; q < 2; q++) {
      int r = q * 32 + trow;
      int gs = tslot ^ (r & 7);
      gl2lds16(Ab + (size_t)r * NN + ks * 64 + 8 * gs, la + q * 2048);
      gl2lds16(Bt + (size_t)r * NN + ks * 64 + 8 * gs, lb + q * 2048);
    }
  };

  stage(0, 0);
  __syncthreads();
  int cur = 0;
#pragma unroll 1
  for (int ks = 0; ks < NT; ++ks) {
    if (ks + 1 < NT) stage(cur ^ 1, ks + 1);
    const bf16* sa = lA[cur];
    const bf16* sb = lB[cur];
    short8 af[2][2], bfr[2][2];
#pragma unroll
    for (int kk = 0; kk < 2; kk++) {
#pragma unroll
      for (int mf = 0; mf < 2; mf++) {
        int ra = wr * 32 + mf * 16 + r16;
        int slot = ((kk << 2) | kb) ^ (ra & 7);
        af[kk][mf] = *reinterpret_cast<const short8*>(&sa[ra * 64 + slot * 8]);
      }
#pragma unroll
      for (int nf = 0; nf < 2; nf++) {
        int rbr = wc * 32 + nf * 16 + r16;
        int slot = ((kk << 2) | kb) ^ (rbr & 7);
        bfr[kk][nf] = *reinterpret_cast<const short8*>(&sb[rbr * 64 + slot * 8]);
      }
    }
    __builtin_amdgcn_s_setprio(1);
#pragma unroll
    for (int kk = 0; kk < 2; kk++)
#pragma unroll
      for (int mf = 0; mf < 2; mf++)
#pragma unroll
        for (int nf = 0; nf < 2; nf++)
          acc[mf][nf] = __builtin_amdgcn_mfma_f32_16x16x32_bf16(
              af[kk][mf], bfr[kk][nf], acc[mf][nf], 0, 0, 0);
    __builtin_amdgcn_s_setprio(0);
    __syncthreads();
    cur ^= 1;
  }

  float bv[2];
#pragma unroll
  for (int nf = 0; nf < 2; nf++) bv[nf] = bias[o0 + wc * 32 + nf * 16 + r16];
#pragma unroll
  for (int mf = 0; mf < 2; mf++) {
    int ng = n0 + wr * 32 + mf * 16 + (lane >> 4) * 4;
    float* op0 = out + ((size_t)batch * NN + ng) * FF;
#pragma unroll
    for (int nf = 0; nf < 2; nf++) {
      int o = o0 + wc * 32 + nf * 16 + r16;
      f32x4 v = acc[mf][nf];
      op0[0 * FF + o] = v[0] + bv[nf];
      op0[1 * FF + o] = v[1] + bv[nf];
      op0[2 * FF + o] = v[2] + bv[nf];
      op0[3 * FF + o] = v[3] + bv[nf];
    }
  }
}

extern "C" void kernel_launch(void* const* d_in, const int* in_sizes, int n_in,
                              void* d_out, int out_size, void* d_ws, size_t ws_size,
                              hipStream_t stream) {
  const float* x    = (const float*)d_in[0];
  const float* adj  = (const float*)d_in[1];
  const float* W    = (const float*)d_in[2];
  const float* bias = (const float*)d_in[3];
  float* out = (float*)d_out;

  char* ws = (char*)d_ws;
  float* dis  = (float*)ws;                              // 64 KB
  bf16* WT    = (bf16*)(ws + (64 << 10));                // 128 KB
  bf16* gT    = (bf16*)(ws + (192 << 10));               // 8 MB
  bf16* adjBF = (bf16*)(ws + (192 << 10) + (8 << 20));   // 64 MB

  degconv_wt_kernel<<<BB * NN / 4 + 64, 256, 0, stream>>>(adj, W, dis, WT, adjBF);
  gemm1_kernel<<<256, 256, 0, stream>>>(x, WT, dis, gT);
  gemm2_kernel<<<1024, 256, 0, stream>>>(adjBF, gT, bias, out);
}